// Round 2
// baseline (400.591 us; speedup 1.0000x reference)
//
#include <hip/hip_runtime.h>
#include <math.h>

#define BB 8
#define NN 2048
#define TN 4096
#define DD 64

typedef __attribute__((ext_vector_type(8))) short short8;
typedef __attribute__((ext_vector_type(4))) float f32x4;

__device__ __forceinline__ unsigned short f2bf(float f) {
    union { float f; unsigned int i; } v; v.f = f;
    unsigned int r = v.i + 0x7FFF + ((v.i >> 16) & 1);   // RNE
    return (unsigned short)(r >> 16);
}

// K1: Wh = concat(ht,h) @ W  (f32), s1 = Wh@a1, s2 = Wh@a2
// one wave per row m; lane = output feature d
__global__ void k1_wh(const float* __restrict__ h,
                      const float* __restrict__ ht,
                      const float* __restrict__ W,
                      const float* __restrict__ a1,
                      const float* __restrict__ a2,
                      float* __restrict__ Wh,
                      float* __restrict__ s1, float* __restrict__ s2) {
    int tid = threadIdx.x;
    int w = tid >> 6, l = tid & 63;
    int rowglob = blockIdx.x * 4 + w;          // b*TN + m, grid.x = BB*TN/4
    int b = rowglob >> 12;
    int m = rowglob & (TN - 1);
    const float* src = (m < NN) ? (ht + ((size_t)b * NN + m) * DD)
                                : (h  + ((size_t)b * NN + (m - NN)) * DD);
    float acc = 0.f;
    #pragma unroll
    for (int k = 0; k < 64; ++k) {
        acc += src[k] * W[k * 64 + l];         // src: wave-uniform broadcast; W: coalesced
    }
    Wh[((size_t)b * TN + m) * DD + l] = acc;
    float r1 = acc * a1[l];
    float r2 = acc * a2[l];
    #pragma unroll
    for (int off = 32; off > 0; off >>= 1) {
        r1 += __shfl_xor(r1, off, 64);
        r2 += __shfl_xor(r2, off, 64);
    }
    if (l == 0) {
        s1[(size_t)b * TN + m] = r1;
        s2[(size_t)b * TN + m] = r2;
    }
}

// K2: S[b][j] = sum_i (adj[i][j]>0) * exp(lrelu(s1[b][i]+s2[b][j]))
// thread = column j; loop 128 rows; all 8 batches per adj load; atomicAdd partials
__global__ void k2_stats(const float* __restrict__ adj,
                         const float* __restrict__ s1,
                         const float* __restrict__ s2,
                         float* __restrict__ S) {
    __shared__ float s1s[8][128];
    int tid = threadIdx.x;
    int j = blockIdx.x * 256 + tid;
    int i0 = blockIdx.y * 128;
    for (int e = tid; e < 8 * 128; e += 256) {
        int b = e >> 7, ii = e & 127;
        s1s[b][ii] = s1[(size_t)b * TN + i0 + ii];
    }
    __syncthreads();
    float s2r[8], acc[8];
    #pragma unroll
    for (int b = 0; b < 8; ++b) {
        s2r[b] = s2[(size_t)b * TN + j];
        acc[b] = 0.f;
    }
    for (int ii = 0; ii < 128; ++ii) {
        float av = adj[(size_t)(i0 + ii) * TN + j];  // coalesced
        if (av != 0.f) {
            #pragma unroll
            for (int b = 0; b < 8; ++b) {
                float v = s1s[b][ii] + s2r[b];
                float lr = fmaxf(v, 0.2f * v);     // LeakyReLU(0.2)
                acc[b] += __expf(lr);
            }
        }
    }
    #pragma unroll
    for (int b = 0; b < 8; ++b) atomicAdd(&S[(size_t)b * TN + j], acc[b]);
}

// K3: Whn_t[b][d][j] = Wh[b][j][d] / S[b][j]  (bf16, transposed for B-operand)
__global__ void k3_whn(const float* __restrict__ Wh,
                       const float* __restrict__ S,
                       unsigned short* __restrict__ Wt) {
    __shared__ float tile[64][65];
    __shared__ float rs[64];
    int b = blockIdx.y;
    int j0 = blockIdx.x * 64;
    int tid = threadIdx.x;
    if (tid < 64) rs[tid] = 1.0f / S[(size_t)b * TN + j0 + tid];
    for (int e = tid; e < 4096; e += 256) {
        int j = e >> 6, d = e & 63;
        tile[j][d] = Wh[((size_t)b * TN + j0 + j) * DD + d];
    }
    __syncthreads();
    for (int e = tid; e < 4096; e += 256) {
        int d = e >> 6, j = e & 63;
        Wt[((size_t)b * DD + d) * TN + j0 + j] = f2bf(tile[j][d] * rs[j]);
    }
}

// K4: hp[i][d] = sum_j P[i][j] * Whn[j][d] with P computed on the fly in
// MFMA A-fragment layout (no LDS). Epilogue: concat remap + ELU + f32 store.
// block = 256 thr (4 waves), i-tile = 64 rows (wave w -> rows i0+16w..+15), full d=64.
__global__ __launch_bounds__(256) void k4_pv(
    const float* __restrict__ adj,
    const float* __restrict__ s1,
    const float* __restrict__ s2,
    const unsigned short* __restrict__ Wt,
    float* __restrict__ out) {
    int b = blockIdx.y;
    int i0 = blockIdx.x * 64;
    int tid = threadIdx.x;
    int w = tid >> 6, l = tid & 63;
    int m = l & 15, q = l >> 4;
    int irow = i0 + w * 16 + m;
    float s1v = s1[(size_t)b * TN + irow];
    const float* s2b = s2 + (size_t)b * TN;
    const unsigned short* wtb = Wt + (size_t)b * DD * TN;
    const float* adjrow = adj + (size_t)irow * TN;

    f32x4 acc[4];
    #pragma unroll
    for (int dt = 0; dt < 4; ++dt) acc[dt] = (f32x4){0.f, 0.f, 0.f, 0.f};

    for (int jt = 0; jt < 32; ++jt) {
        int j0 = jt * 128;
        // B fragments: lane holds Whn_t[d0+m][j0+32t+8q .. +7] (16B contiguous)
        short8 bfrag[4][4];
        #pragma unroll
        for (int dt = 0; dt < 4; ++dt) {
            #pragma unroll
            for (int t = 0; t < 4; ++t) {
                const unsigned short* p =
                    wtb + (size_t)(dt * 16 + m) * TN + j0 + t * 32 + q * 8;
                bfrag[dt][t] = *reinterpret_cast<const short8*>(p);
            }
        }
        #pragma unroll
        for (int t = 0; t < 4; ++t) {
            int jb = j0 + t * 32 + q * 8;
            f32x4 av0 = *reinterpret_cast<const f32x4*>(adjrow + jb);
            f32x4 av1 = *reinterpret_cast<const f32x4*>(adjrow + jb + 4);
            f32x4 sA = *reinterpret_cast<const f32x4*>(s2b + jb);
            f32x4 sB = *reinterpret_cast<const f32x4*>(s2b + jb + 4);
            short8 af;
            #pragma unroll
            for (int jj = 0; jj < 8; ++jj) {
                float av = (jj < 4) ? av0[jj] : av1[jj - 4];
                float sj = (jj < 4) ? sA[jj] : sB[jj - 4];
                float e = s1v + sj;
                float lr = fmaxf(e, 0.2f * e);
                float pv = (av != 0.f) ? __expf(lr) : 0.f;
                af[jj] = (short)f2bf(pv);
            }
            #pragma unroll
            for (int dt = 0; dt < 4; ++dt)
                acc[dt] = __builtin_amdgcn_mfma_f32_16x16x32_bf16(
                    af, bfrag[dt][t], acc[dt], 0, 0, 0);
        }
    }

    // epilogue: C row = q*4+r, col = dt*16+m
    int gbase = i0 + w * 16 + q * 4;
    #pragma unroll
    for (int dt = 0; dt < 4; ++dt) {
        int d = dt * 16 + m;
        #pragma unroll
        for (int r = 0; r < 4; ++r) {
            int g = gbase + r;
            float f = acc[dt][r];
            float o = (f > 0.f) ? f : expm1f(f);     // ELU alpha=1
            size_t off = (g < NN) ? ((size_t)(b * NN + g) * 128 + d)
                                  : ((size_t)(b * NN + (g - NN)) * 128 + 64 + d);
            out[off] = o;
        }
    }
}

extern "C" void kernel_launch(void* const* d_in, const int* in_sizes, int n_in,
                              void* d_out, int out_size, void* d_ws, size_t ws_size,
                              hipStream_t stream) {
    const float* h   = (const float*)d_in[0];
    const float* ht  = (const float*)d_in[1];
    const float* W   = (const float*)d_in[2];
    const float* a1  = (const float*)d_in[3];
    const float* a2  = (const float*)d_in[4];
    const float* adj = (const float*)d_in[5];
    float* out = (float*)d_out;

    char* ws = (char*)d_ws;
    float* Wh          = (float*)(ws);                                   // 8 MB
    unsigned short* Wt = (unsigned short*)(ws + (8 << 20));              // 4 MB
    float* s1          = (float*)(ws + (12 << 20));                      // 128 KB
    float* s2          = (float*)(ws + (12 << 20) + (128 << 10));        // 128 KB
    float* S           = (float*)(ws + (12 << 20) + (256 << 10));        // 128 KB

    hipMemsetAsync(S, 0, (size_t)BB * TN * sizeof(float), stream);
    k1_wh<<<dim3(BB * TN / 4), dim3(256), 0, stream>>>(h, ht, W, a1, a2, Wh, s1, s2);
    k2_stats<<<dim3(16, 32), dim3(256), 0, stream>>>(adj, s1, s2, S);
    k3_whn<<<dim3(64, 8), dim3(256), 0, stream>>>(Wh, S, Wt);
    k4_pv<<<dim3(64, 8), dim3(256), 0, stream>>>(adj, s1, s2, Wt, out);
}

// Round 3
// 384.184 us; speedup vs baseline: 1.0427x; 1.0427x over previous
//
#include <hip/hip_runtime.h>
#include <math.h>

#define BB 8
#define NN 2048
#define TN 4096
#define DD 64

typedef __attribute__((ext_vector_type(8))) short short8;
typedef __attribute__((ext_vector_type(4))) float f32x4;

__device__ __forceinline__ unsigned short f2bf(float f) {
    union { float f; unsigned int i; } v; v.f = f;
    unsigned int r = v.i + 0x7FFF + ((v.i >> 16) & 1);   // RNE
    return (unsigned short)(r >> 16);
}

// K1: Wh = concat(ht,h) @ W (f32); s1 = Wh@a1, s2 = Wh@a2; store exp tables
// E1p=exp(s1), E1n=exp(0.2 s1), E2p=exp(s2), E2n=exp(0.2 s2).
__global__ void k1_wh(const float* __restrict__ h,
                      const float* __restrict__ ht,
                      const float* __restrict__ W,
                      const float* __restrict__ a1,
                      const float* __restrict__ a2,
                      float* __restrict__ Wh,
                      float* __restrict__ E1p, float* __restrict__ E1n,
                      float* __restrict__ E2p, float* __restrict__ E2n) {
    int tid = threadIdx.x;
    int w = tid >> 6, l = tid & 63;
    int rowglob = blockIdx.x * 4 + w;          // b*TN + m
    int b = rowglob >> 12;
    int m = rowglob & (TN - 1);
    const float* src = (m < NN) ? (ht + ((size_t)b * NN + m) * DD)
                                : (h  + ((size_t)b * NN + (m - NN)) * DD);
    float acc = 0.f;
    #pragma unroll
    for (int k = 0; k < 64; ++k) {
        acc += src[k] * W[k * 64 + l];
    }
    Wh[((size_t)b * TN + m) * DD + l] = acc;
    float r1 = acc * a1[l];
    float r2 = acc * a2[l];
    #pragma unroll
    for (int off = 32; off > 0; off >>= 1) {
        r1 += __shfl_xor(r1, off, 64);
        r2 += __shfl_xor(r2, off, 64);
    }
    if (l == 0) {
        size_t o = (size_t)b * TN + m;
        E1p[o] = __expf(r1);
        E1n[o] = __expf(0.2f * r1);
        E2p[o] = __expf(r2);
        E2n[o] = __expf(0.2f * r2);
    }
}

// K2: S[b][j] = sum_i adj[i][j]!=0 ? max(E1p_i*E2p_j, E1n_i*E2n_j) : 0
// branchless, no transcendentals. thread = column j, 64-row chunks.
__global__ void k2_stats(const float* __restrict__ adj,
                         const float* __restrict__ E1p, const float* __restrict__ E1n,
                         const float* __restrict__ E2p, const float* __restrict__ E2n,
                         float* __restrict__ S) {
    __shared__ float e1ps[8][64], e1ns[8][64];
    int tid = threadIdx.x;
    int j = blockIdx.x * 256 + tid;
    int i0 = blockIdx.y * 64;
    for (int e = tid; e < 8 * 64; e += 256) {
        int b = e >> 6, ii = e & 63;
        e1ps[b][ii] = E1p[(size_t)b * TN + i0 + ii];
        e1ns[b][ii] = E1n[(size_t)b * TN + i0 + ii];
    }
    __syncthreads();
    float e2p[8], e2n[8], acc[8];
    #pragma unroll
    for (int b = 0; b < 8; ++b) {
        e2p[b] = E2p[(size_t)b * TN + j];
        e2n[b] = E2n[(size_t)b * TN + j];
        acc[b] = 0.f;
    }
    for (int ii = 0; ii < 64; ++ii) {
        float av = adj[(size_t)(i0 + ii) * TN + j];  // coalesced
        #pragma unroll
        for (int b = 0; b < 8; ++b) {
            float v = fmaxf(e1ps[b][ii] * e2p[b], e1ns[b][ii] * e2n[b]);
            acc[b] += (av != 0.f) ? v : 0.f;
        }
    }
    #pragma unroll
    for (int b = 0; b < 8; ++b) atomicAdd(&S[(size_t)b * TN + j], acc[b]);
}

// K3: Whn_t[b][d][j] = Wh[b][j][d] / S[b][j]  (bf16, transposed for B-operand)
__global__ void k3_whn(const float* __restrict__ Wh,
                       const float* __restrict__ S,
                       unsigned short* __restrict__ Wt) {
    __shared__ float tile[64][65];
    __shared__ float rs[64];
    int b = blockIdx.y;
    int j0 = blockIdx.x * 64;
    int tid = threadIdx.x;
    if (tid < 64) rs[tid] = 1.0f / S[(size_t)b * TN + j0 + tid];
    for (int e = tid; e < 4096; e += 256) {
        int j = e >> 6, d = e & 63;
        tile[j][d] = Wh[((size_t)b * TN + j0 + j) * DD + d];
    }
    __syncthreads();
    for (int e = tid; e < 4096; e += 256) {
        int d = e >> 6, j = e & 63;
        Wt[((size_t)b * DD + d) * TN + j0 + j] = f2bf(tile[j][d] * rs[j]);
    }
}

// K4: partial hp[i][d] += sum_{j in js-range} P[i][j] * Whn[j][d], P on the fly
// in MFMA A-layout, no exp. Grid (64 i-tiles, 4 j-splits, 8 b). atomicAdd f32.
__global__ __launch_bounds__(256) void k4_pv(
    const float* __restrict__ adj,
    const float* __restrict__ E1p, const float* __restrict__ E1n,
    const float* __restrict__ E2p, const float* __restrict__ E2n,
    const unsigned short* __restrict__ Wt,
    float* __restrict__ hp) {
    int b = blockIdx.z;
    int js = blockIdx.y;
    int i0 = blockIdx.x * 64;
    int tid = threadIdx.x;
    int w = tid >> 6, l = tid & 63;
    int m = l & 15, q = l >> 4;
    int irow = i0 + w * 16 + m;
    float e1p_v = E1p[(size_t)b * TN + irow];
    float e1n_v = E1n[(size_t)b * TN + irow];
    const float* e2pb = E2p + (size_t)b * TN;
    const float* e2nb = E2n + (size_t)b * TN;
    const unsigned short* wtb = Wt + (size_t)b * DD * TN;
    const float* adjrow = adj + (size_t)irow * TN;

    f32x4 acc[4];
    #pragma unroll
    for (int dt = 0; dt < 4; ++dt) acc[dt] = (f32x4){0.f, 0.f, 0.f, 0.f};

    for (int jt = 0; jt < 8; ++jt) {
        int j0 = js * 1024 + jt * 128;
        short8 bfrag[4][4];
        #pragma unroll
        for (int dt = 0; dt < 4; ++dt) {
            #pragma unroll
            for (int t = 0; t < 4; ++t) {
                const unsigned short* p =
                    wtb + (size_t)(dt * 16 + m) * TN + j0 + t * 32 + q * 8;
                bfrag[dt][t] = *reinterpret_cast<const short8*>(p);
            }
        }
        #pragma unroll
        for (int t = 0; t < 4; ++t) {
            int jb = j0 + t * 32 + q * 8;
            f32x4 av0 = *reinterpret_cast<const f32x4*>(adjrow + jb);
            f32x4 av1 = *reinterpret_cast<const f32x4*>(adjrow + jb + 4);
            f32x4 p20 = *reinterpret_cast<const f32x4*>(e2pb + jb);
            f32x4 p21 = *reinterpret_cast<const f32x4*>(e2pb + jb + 4);
            f32x4 n20 = *reinterpret_cast<const f32x4*>(e2nb + jb);
            f32x4 n21 = *reinterpret_cast<const f32x4*>(e2nb + jb + 4);
            short8 af;
            #pragma unroll
            for (int jj = 0; jj < 8; ++jj) {
                float av = (jj < 4) ? av0[jj] : av1[jj - 4];
                float p2 = (jj < 4) ? p20[jj] : p21[jj - 4];
                float n2 = (jj < 4) ? n20[jj] : n21[jj - 4];
                float v = fmaxf(e1p_v * p2, e1n_v * n2);
                float pv = (av != 0.f) ? v : 0.f;
                af[jj] = (short)f2bf(pv);
            }
            #pragma unroll
            for (int dt = 0; dt < 4; ++dt)
                acc[dt] = __builtin_amdgcn_mfma_f32_16x16x32_bf16(
                    af, bfrag[dt][t], acc[dt], 0, 0, 0);
        }
    }

    // accumulate partials: C row = q*4+r, col = dt*16+m
    int gbase = i0 + w * 16 + q * 4;
    #pragma unroll
    for (int dt = 0; dt < 4; ++dt) {
        int d = dt * 16 + m;
        #pragma unroll
        for (int r = 0; r < 4; ++r) {
            int g = gbase + r;
            atomicAdd(&hp[((size_t)b * TN + g) * DD + d], acc[dt][r]);
        }
    }
}

// K5: out[b][n][0:64]=elu(hp[b][n]), out[b][n][64:128]=elu(hp[b][n+2048]); float4
__global__ void k5_epi(const float* __restrict__ hp, float* __restrict__ out) {
    int t = blockIdx.x * 256 + threadIdx.x;       // < 524288
    int d4 = t & 31;
    int n = (t >> 5) & 2047;
    int b = t >> 16;
    int g, sd;
    if (d4 < 16) { g = n;        sd = d4 * 4; }
    else         { g = n + NN;   sd = (d4 - 16) * 4; }
    f32x4 v = *reinterpret_cast<const f32x4*>(hp + ((size_t)b * TN + g) * DD + sd);
    f32x4 r;
    #pragma unroll
    for (int c = 0; c < 4; ++c) r[c] = (v[c] > 0.f) ? v[c] : expm1f(v[c]);
    *reinterpret_cast<f32x4*>(out + ((size_t)b * NN + n) * 128 + d4 * 4) = r;
}

extern "C" void kernel_launch(void* const* d_in, const int* in_sizes, int n_in,
                              void* d_out, int out_size, void* d_ws, size_t ws_size,
                              hipStream_t stream) {
    const float* h   = (const float*)d_in[0];
    const float* ht  = (const float*)d_in[1];
    const float* W   = (const float*)d_in[2];
    const float* a1  = (const float*)d_in[3];
    const float* a2  = (const float*)d_in[4];
    const float* adj = (const float*)d_in[5];
    float* out = (float*)d_out;

    char* ws = (char*)d_ws;
    float* Wh          = (float*)(ws);                                   // 8 MB (reused as hp)
    unsigned short* Wt = (unsigned short*)(ws + (8 << 20));              // 4 MB
    float* S           = (float*)(ws + (12 << 20));                      // 128 KB
    float* E1p         = (float*)(ws + (12 << 20) + (128 << 10));
    float* E1n         = (float*)(ws + (12 << 20) + (256 << 10));
    float* E2p         = (float*)(ws + (12 << 20) + (384 << 10));
    float* E2n         = (float*)(ws + (12 << 20) + (512 << 10));
    float* hp          = Wh;   // Wh is dead after k3; reuse as accumulator

    hipMemsetAsync(S, 0, (size_t)BB * TN * sizeof(float), stream);
    k1_wh<<<dim3(BB * TN / 4), dim3(256), 0, stream>>>(h, ht, W, a1, a2, Wh,
                                                       E1p, E1n, E2p, E2n);
    k2_stats<<<dim3(16, 64), dim3(256), 0, stream>>>(adj, E1p, E1n, E2p, E2n, S);
    k3_whn<<<dim3(64, 8), dim3(256), 0, stream>>>(Wh, S, Wt);
    hipMemsetAsync(hp, 0, (size_t)BB * TN * DD * sizeof(float), stream);
    k4_pv<<<dim3(64, 4, 8), dim3(256), 0, stream>>>(adj, E1p, E1n, E2p, E2n, Wt, hp);
    k5_epi<<<dim3(2048), dim3(256), 0, stream>>>(hp, out);
}

// Round 4
// 352.497 us; speedup vs baseline: 1.1364x; 1.0899x over previous
//
#include <hip/hip_runtime.h>
#include <hip/hip_bf16.h>
#include <math.h>

#define BB 8
#define NN 2048
#define TN 4096
#define DD 64

typedef __attribute__((ext_vector_type(8))) short short8;
typedef __attribute__((ext_vector_type(4))) float f32x4;
typedef __attribute__((ext_vector_type(4))) unsigned int u32x4;

__device__ __forceinline__ unsigned short f2bf(float f) {
    union { float f; unsigned int i; } v; v.f = f;
    unsigned int r = v.i + 0x7FFF + ((v.i >> 16) & 1);   // RNE
    return (unsigned short)(r >> 16);
}

// K0: adj (64 MB f32) -> row-major bitmask (2 MB). bit j of row i = adj[i][j]!=0
// wave covers a 256-j strip via 4 ballots of 64 consecutive j each.
__global__ void k0_mask(const float* __restrict__ adj,
                        unsigned long long* __restrict__ rowmask) {
    int tid = threadIdx.x;
    int w = tid >> 6, l = tid & 63;
    int jbase = blockIdx.x * 1024 + w * 256;
    int i0 = blockIdx.y * 32;
    for (int r = 0; r < 32; ++r) {
        int i = i0 + r;
        const float* row = adj + (size_t)i * TN + jbase;
        unsigned long long b0 = __ballot(row[l] != 0.f);
        unsigned long long b1 = __ballot(row[64 + l] != 0.f);
        unsigned long long b2 = __ballot(row[128 + l] != 0.f);
        unsigned long long b3 = __ballot(row[192 + l] != 0.f);
        if (l == 0) {
            unsigned long long* dst = rowmask + (size_t)i * 64 + (jbase >> 6);
            dst[0] = b0; dst[1] = b1; dst[2] = b2; dst[3] = b3;
        }
    }
}

// K1: Wh = concat(ht,h) @ W (f32); s1 = Wh@a1, s2 = Wh@a2; store exp tables
__global__ void k1_wh(const float* __restrict__ h,
                      const float* __restrict__ ht,
                      const float* __restrict__ W,
                      const float* __restrict__ a1,
                      const float* __restrict__ a2,
                      float* __restrict__ Wh,
                      float* __restrict__ E1p, float* __restrict__ E1n,
                      float* __restrict__ E2p, float* __restrict__ E2n) {
    int tid = threadIdx.x;
    int w = tid >> 6, l = tid & 63;
    int rowglob = blockIdx.x * 4 + w;          // b*TN + m
    int b = rowglob >> 12;
    int m = rowglob & (TN - 1);
    const float* src = (m < NN) ? (ht + ((size_t)b * NN + m) * DD)
                                : (h  + ((size_t)b * NN + (m - NN)) * DD);
    float acc = 0.f;
    #pragma unroll
    for (int k = 0; k < 64; ++k) {
        acc += src[k] * W[k * 64 + l];
    }
    Wh[((size_t)b * TN + m) * DD + l] = acc;
    float r1 = acc * a1[l];
    float r2 = acc * a2[l];
    #pragma unroll
    for (int off = 32; off > 0; off >>= 1) {
        r1 += __shfl_xor(r1, off, 64);
        r2 += __shfl_xor(r2, off, 64);
    }
    if (l == 0) {
        size_t o = (size_t)b * TN + m;
        E1p[o] = __expf(r1);
        E1n[o] = __expf(0.2f * r1);
        E2p[o] = __expf(r2);
        E2n[o] = __expf(0.2f * r2);
    }
}

// K2: S[b][j] = sum_i bit(i,j) * max(E1p_i*E2p_j, E1n_i*E2n_j)
// bitmask via LDS tile (128 i x 256 j). branchless, no adj values.
__global__ __launch_bounds__(256) void k2_stats(
    const unsigned int* __restrict__ rowmask32,
    const float* __restrict__ E1p, const float* __restrict__ E1n,
    const float* __restrict__ E2p, const float* __restrict__ E2n,
    float* __restrict__ S) {
    __shared__ unsigned int msk[128][8];
    __shared__ float e1ps[8][128], e1ns[8][128];
    int tid = threadIdx.x;
    int j0 = blockIdx.x * 256;
    int i0 = blockIdx.y * 128;
    int j = j0 + tid;
    for (int e = tid; e < 1024; e += 256) {
        int r = e >> 3, c = e & 7;
        msk[r][c] = rowmask32[(size_t)(i0 + r) * 128 + (j0 >> 5) + c];
    }
    for (int e = tid; e < 1024; e += 256) {
        int b = e >> 7, r = e & 127;
        e1ps[b][r] = E1p[(size_t)b * TN + i0 + r];
        e1ns[b][r] = E1n[(size_t)b * TN + i0 + r];
    }
    __syncthreads();
    float e2p[8], e2n[8], acc[8];
    #pragma unroll
    for (int b = 0; b < 8; ++b) {
        e2p[b] = E2p[(size_t)b * TN + j];
        e2n[b] = E2n[(size_t)b * TN + j];
        acc[b] = 0.f;
    }
    int jw = tid >> 5, jb = tid & 31;
    for (int i = 0; i < 128; ++i) {
        unsigned int bit = (msk[i][jw] >> jb) & 1u;
        #pragma unroll
        for (int b = 0; b < 8; ++b) {
            float v = fmaxf(e1ps[b][i] * e2p[b], e1ns[b][i] * e2n[b]);
            acc[b] += bit ? v : 0.f;
        }
    }
    #pragma unroll
    for (int b = 0; b < 8; ++b) atomicAdd(&S[(size_t)b * TN + j], acc[b]);
}

// K3: Whn_t[b][d][j] = Wh[b][j][d] / S[b][j]  (bf16, transposed for B-operand)
__global__ void k3_whn(const float* __restrict__ Wh,
                       const float* __restrict__ S,
                       unsigned short* __restrict__ Wt) {
    __shared__ float tile[64][65];
    __shared__ float rs[64];
    int b = blockIdx.y;
    int j0 = blockIdx.x * 64;
    int tid = threadIdx.x;
    if (tid < 64) rs[tid] = 1.0f / S[(size_t)b * TN + j0 + tid];
    for (int e = tid; e < 4096; e += 256) {
        int j = e >> 6, d = e & 63;
        tile[j][d] = Wh[((size_t)b * TN + j0 + j) * DD + d];
    }
    __syncthreads();
    for (int e = tid; e < 4096; e += 256) {
        int d = e >> 6, j = e & 63;
        Wt[((size_t)b * DD + d) * TN + j0 + j] = f2bf(tile[j][d] * rs[j]);
    }
}

// K4: partial hp[i][d] += sum_j P[i][j]*Whn[j][d]; P on the fly in MFMA A-layout
// from the 2 MB L2-resident bitmask. Grid (64 i-tiles, 4 j-splits, 8 b).
__global__ __launch_bounds__(256, 4) void k4_pv(
    const unsigned int* __restrict__ rowmask32,
    const float* __restrict__ E1p, const float* __restrict__ E1n,
    const float* __restrict__ E2p, const float* __restrict__ E2n,
    const unsigned short* __restrict__ Wt,
    float* __restrict__ hp) {
    int b = blockIdx.z;
    int js = blockIdx.y;
    int i0 = blockIdx.x * 64;
    int tid = threadIdx.x;
    int w = tid >> 6, l = tid & 63;
    int m = l & 15, q = l >> 4;
    int irow = i0 + w * 16 + m;
    float e1p_v = E1p[(size_t)b * TN + irow];
    float e1n_v = E1n[(size_t)b * TN + irow];
    const float* e2pb = E2p + (size_t)b * TN;
    const float* e2nb = E2n + (size_t)b * TN;
    const unsigned short* wtb = Wt + (size_t)b * DD * TN;
    const unsigned int* mrow = rowmask32 + (size_t)irow * 128;

    f32x4 acc[4];
    #pragma unroll
    for (int dt = 0; dt < 4; ++dt) acc[dt] = (f32x4){0.f, 0.f, 0.f, 0.f};

    for (int jt = 0; jt < 8; ++jt) {
        int j0 = js * 1024 + jt * 128;
        u32x4 m4 = *reinterpret_cast<const u32x4*>(mrow + (j0 >> 5));
        short8 bfrag[4][4];
        #pragma unroll
        for (int dt = 0; dt < 4; ++dt) {
            #pragma unroll
            for (int t = 0; t < 4; ++t) {
                const unsigned short* p =
                    wtb + (size_t)(dt * 16 + m) * TN + j0 + t * 32 + q * 8;
                bfrag[dt][t] = *reinterpret_cast<const short8*>(p);
            }
        }
        #pragma unroll
        for (int t = 0; t < 4; ++t) {
            int jb = j0 + t * 32 + q * 8;
            unsigned int bytev = (m4[t] >> (q * 8)) & 0xFFu;
            f32x4 p20 = *reinterpret_cast<const f32x4*>(e2pb + jb);
            f32x4 p21 = *reinterpret_cast<const f32x4*>(e2pb + jb + 4);
            f32x4 n20 = *reinterpret_cast<const f32x4*>(e2nb + jb);
            f32x4 n21 = *reinterpret_cast<const f32x4*>(e2nb + jb + 4);
            union { unsigned int u[4]; short8 s; } af;
            #pragma unroll
            for (int jp = 0; jp < 4; ++jp) {
                int j0i = 2 * jp, j1i = 2 * jp + 1;
                float pa = (j0i < 4) ? p20[j0i] : p21[j0i - 4];
                float na = (j0i < 4) ? n20[j0i] : n21[j0i - 4];
                float pb2 = (j1i < 4) ? p20[j1i] : p21[j1i - 4];
                float nb2 = (j1i < 4) ? n20[j1i] : n21[j1i - 4];
                float v0 = fmaxf(e1p_v * pa, e1n_v * na);
                float v1 = fmaxf(e1p_v * pb2, e1n_v * nb2);
                v0 = (bytev & (1u << j0i)) ? v0 : 0.f;
                v1 = (bytev & (1u << j1i)) ? v1 : 0.f;
                __hip_bfloat162 hb = __float22bfloat162_rn(make_float2(v0, v1));
                af.u[jp] = *reinterpret_cast<unsigned int*>(&hb);
            }
            #pragma unroll
            for (int dt = 0; dt < 4; ++dt)
                acc[dt] = __builtin_amdgcn_mfma_f32_16x16x32_bf16(
                    af.s, bfrag[dt][t], acc[dt], 0, 0, 0);
        }
    }

    // accumulate partials: C row = q*4+r, col = dt*16+m
    int gbase = i0 + w * 16 + q * 4;
    #pragma unroll
    for (int dt = 0; dt < 4; ++dt) {
        int d = dt * 16 + m;
        #pragma unroll
        for (int r = 0; r < 4; ++r) {
            int g = gbase + r;
            atomicAdd(&hp[((size_t)b * TN + g) * DD + d], acc[dt][r]);
        }
    }
}

// K5: out[b][n][0:64]=elu(hp[b][n]), out[b][n][64:128]=elu(hp[b][n+2048]); float4
__global__ void k5_epi(const float* __restrict__ hp, float* __restrict__ out) {
    int t = blockIdx.x * 256 + threadIdx.x;       // < 524288
    int d4 = t & 31;
    int n = (t >> 5) & 2047;
    int b = t >> 16;
    int g, sd;
    if (d4 < 16) { g = n;        sd = d4 * 4; }
    else         { g = n + NN;   sd = (d4 - 16) * 4; }
    f32x4 v = *reinterpret_cast<const f32x4*>(hp + ((size_t)b * TN + g) * DD + sd);
    f32x4 r;
    #pragma unroll
    for (int c = 0; c < 4; ++c) r[c] = (v[c] > 0.f) ? v[c] : expm1f(v[c]);
    *reinterpret_cast<f32x4*>(out + ((size_t)b * NN + n) * 128 + d4 * 4) = r;
}

extern "C" void kernel_launch(void* const* d_in, const int* in_sizes, int n_in,
                              void* d_out, int out_size, void* d_ws, size_t ws_size,
                              hipStream_t stream) {
    const float* h   = (const float*)d_in[0];
    const float* ht  = (const float*)d_in[1];
    const float* W   = (const float*)d_in[2];
    const float* a1  = (const float*)d_in[3];
    const float* a2  = (const float*)d_in[4];
    const float* adj = (const float*)d_in[5];
    float* out = (float*)d_out;

    char* ws = (char*)d_ws;
    float* Wh          = (float*)(ws);                                   // 8 MB (reused as hp)
    unsigned short* Wt = (unsigned short*)(ws + (8 << 20));              // 4 MB
    float* S           = (float*)(ws + (12 << 20));                      // 128 KB
    float* E1p         = (float*)(ws + (12 << 20) + (128 << 10));
    float* E1n         = (float*)(ws + (12 << 20) + (256 << 10));
    float* E2p         = (float*)(ws + (12 << 20) + (384 << 10));
    float* E2n         = (float*)(ws + (12 << 20) + (512 << 10));
    unsigned long long* rowmask = (unsigned long long*)(ws + (12 << 20) + (640 << 10)); // 2 MB
    const unsigned int* rowmask32 = (const unsigned int*)rowmask;
    float* hp          = Wh;   // Wh dead after k3; reuse as accumulator

    hipMemsetAsync(S, 0, (size_t)BB * TN * sizeof(float), stream);
    k0_mask<<<dim3(4, 128), dim3(256), 0, stream>>>(adj, rowmask);
    k1_wh<<<dim3(BB * TN / 4), dim3(256), 0, stream>>>(h, ht, W, a1, a2, Wh,
                                                       E1p, E1n, E2p, E2n);
    k2_stats<<<dim3(16, 32), dim3(256), 0, stream>>>(rowmask32, E1p, E1n, E2p, E2n, S);
    k3_whn<<<dim3(64, 8), dim3(256), 0, stream>>>(Wh, S, Wt);
    hipMemsetAsync(hp, 0, (size_t)BB * TN * DD * sizeof(float), stream);
    k4_pv<<<dim3(64, 4, 8), dim3(256), 0, stream>>>(rowmask32, E1p, E1n, E2p, E2n, Wt, hp);
    k5_epi<<<dim3(2048), dim3(256), 0, stream>>>(hp, out);
}

// Round 5
// 256.514 us; speedup vs baseline: 1.5617x; 1.3742x over previous
//
#include <hip/hip_runtime.h>
#include <hip/hip_bf16.h>
#include <math.h>

#define BB 8
#define NN 2048
#define TN 4096
#define DD 64

typedef __attribute__((ext_vector_type(8))) short short8;
typedef __attribute__((ext_vector_type(4))) float f32x4;
typedef __attribute__((ext_vector_type(4))) unsigned int u32x4;

__device__ __forceinline__ unsigned short f2bf(float f) {
    union { float f; unsigned int i; } v; v.f = f;
    unsigned int r = v.i + 0x7FFF + ((v.i >> 16) & 1);   // RNE
    return (unsigned short)(r >> 16);
}

// K0: adj (64 MB f32) -> row-major bitmask (2 MB). bit j of row i = adj[i][j]!=0
__global__ void k0_mask(const float* __restrict__ adj,
                        unsigned long long* __restrict__ rowmask) {
    int tid = threadIdx.x;
    int w = tid >> 6, l = tid & 63;
    int jbase = blockIdx.x * 1024 + w * 256;
    int i0 = blockIdx.y * 32;
    for (int r = 0; r < 32; ++r) {
        int i = i0 + r;
        const float* row = adj + (size_t)i * TN + jbase;
        unsigned long long b0 = __ballot(row[l] != 0.f);
        unsigned long long b1 = __ballot(row[64 + l] != 0.f);
        unsigned long long b2 = __ballot(row[128 + l] != 0.f);
        unsigned long long b3 = __ballot(row[192 + l] != 0.f);
        if (l == 0) {
            unsigned long long* dst = rowmask + (size_t)i * 64 + (jbase >> 6);
            dst[0] = b0; dst[1] = b1; dst[2] = b2; dst[3] = b3;
        }
    }
}

// K1: Wh = concat(ht,h) @ W (f32); s1 = Wh@a1, s2 = Wh@a2; store exp tables
__global__ void k1_wh(const float* __restrict__ h,
                      const float* __restrict__ ht,
                      const float* __restrict__ W,
                      const float* __restrict__ a1,
                      const float* __restrict__ a2,
                      float* __restrict__ Wh,
                      float* __restrict__ E1p, float* __restrict__ E1n,
                      float* __restrict__ E2p, float* __restrict__ E2n) {
    int tid = threadIdx.x;
    int w = tid >> 6, l = tid & 63;
    int rowglob = blockIdx.x * 4 + w;          // b*TN + m
    int b = rowglob >> 12;
    int m = rowglob & (TN - 1);
    const float* src = (m < NN) ? (ht + ((size_t)b * NN + m) * DD)
                                : (h  + ((size_t)b * NN + (m - NN)) * DD);
    const f32x4* src4 = reinterpret_cast<const f32x4*>(src);
    float c0 = 0.f, c1 = 0.f, c2 = 0.f, c3 = 0.f;
    #pragma unroll
    for (int k = 0; k < 16; ++k) {
        f32x4 s = src4[k];                      // wave-uniform 16B broadcast
        c0 += s[0] * W[(k * 4 + 0) * 64 + l];
        c1 += s[1] * W[(k * 4 + 1) * 64 + l];
        c2 += s[2] * W[(k * 4 + 2) * 64 + l];
        c3 += s[3] * W[(k * 4 + 3) * 64 + l];
    }
    float acc = (c0 + c1) + (c2 + c3);
    Wh[((size_t)b * TN + m) * DD + l] = acc;
    float r1 = acc * a1[l];
    float r2 = acc * a2[l];
    #pragma unroll
    for (int off = 32; off > 0; off >>= 1) {
        r1 += __shfl_xor(r1, off, 64);
        r2 += __shfl_xor(r2, off, 64);
    }
    if (l == 0) {
        size_t o = (size_t)b * TN + m;
        E1p[o] = __expf(r1);
        E1n[o] = __expf(0.2f * r1);
        E2p[o] = __expf(r2);
        E2n[o] = __expf(0.2f * r2);
    }
}

// K2: S[b][j] = sum_i bit(i,j) * max(E1p_i*E2p_j, E1n_i*E2n_j)
__global__ __launch_bounds__(256) void k2_stats(
    const unsigned int* __restrict__ rowmask32,
    const float* __restrict__ E1p, const float* __restrict__ E1n,
    const float* __restrict__ E2p, const float* __restrict__ E2n,
    float* __restrict__ S) {
    __shared__ unsigned int msk[128][8];
    __shared__ float e1ps[8][128], e1ns[8][128];
    int tid = threadIdx.x;
    int j0 = blockIdx.x * 256;
    int i0 = blockIdx.y * 128;
    int j = j0 + tid;
    for (int e = tid; e < 1024; e += 256) {
        int r = e >> 3, c = e & 7;
        msk[r][c] = rowmask32[(size_t)(i0 + r) * 128 + (j0 >> 5) + c];
    }
    for (int e = tid; e < 1024; e += 256) {
        int b = e >> 7, r = e & 127;
        e1ps[b][r] = E1p[(size_t)b * TN + i0 + r];
        e1ns[b][r] = E1n[(size_t)b * TN + i0 + r];
    }
    __syncthreads();
    float e2p[8], e2n[8], acc[8];
    #pragma unroll
    for (int b = 0; b < 8; ++b) {
        e2p[b] = E2p[(size_t)b * TN + j];
        e2n[b] = E2n[(size_t)b * TN + j];
        acc[b] = 0.f;
    }
    int jw = tid >> 5, jb = tid & 31;
    for (int i = 0; i < 128; ++i) {
        unsigned int bit = (msk[i][jw] >> jb) & 1u;
        #pragma unroll
        for (int b = 0; b < 8; ++b) {
            float v = fmaxf(e1ps[b][i] * e2p[b], e1ns[b][i] * e2n[b]);
            acc[b] += bit ? v : 0.f;
        }
    }
    #pragma unroll
    for (int b = 0; b < 8; ++b) atomicAdd(&S[(size_t)b * TN + j], acc[b]);
}

// K3: Whn_t[b][d][j] = Wh[b][j][d] / S[b][j]  (bf16, transposed; b128 stores)
__global__ void k3_whn(const float* __restrict__ Wh,
                       const float* __restrict__ S,
                       unsigned short* __restrict__ Wt) {
    __shared__ float tile[64][65];
    __shared__ float rs[64];
    int b = blockIdx.y;
    int j0 = blockIdx.x * 64;
    int tid = threadIdx.x;
    if (tid < 64) rs[tid] = 1.0f / S[(size_t)b * TN + j0 + tid];
    for (int e = tid; e < 4096; e += 256) {
        int j = e >> 6, d = e & 63;
        tile[j][d] = Wh[((size_t)b * TN + j0 + j) * DD + d];
    }
    __syncthreads();
    for (int e = tid; e < 512; e += 256) {
        int d = e >> 3, jg = e & 7;
        union { unsigned short u[8]; short8 s; } pk;
        #pragma unroll
        for (int k = 0; k < 8; ++k) {
            int j = jg * 8 + k;
            pk.u[k] = f2bf(tile[j][d] * rs[j]);
        }
        *reinterpret_cast<short8*>(Wt + ((size_t)b * DD + d) * TN + j0 + jg * 8) = pk.s;
    }
}

// K4: partial hp[i][d] += sum_j P[i][j]*Whn[j][d].
// 512 thr (8 waves), i-tile 128, j-split 4, b pinned to XCD via blockIdx&7.
// B tile (128j x 64d, 16 KB) LDS-staged once per jt with register double-buffer.
__global__ __launch_bounds__(512, 4) void k4_pv(
    const unsigned int* __restrict__ rowmask32,
    const float* __restrict__ E1p, const float* __restrict__ E1n,
    const float* __restrict__ E2p, const float* __restrict__ E2n,
    const unsigned short* __restrict__ Wt,
    float* __restrict__ hp) {
    __shared__ unsigned short wt_s[64 * 136];   // 136 = 128 + 8 pad (2-way-free banks)
    int bx = blockIdx.x;
    int b  = bx & 7;                 // consecutive blocks -> XCD round-robin
    int js = (bx >> 3) & 3;
    int i0 = (bx >> 5) * 128;
    int tid = threadIdx.x;
    int w = tid >> 6, l = tid & 63;
    int m = l & 15, q = l >> 4;
    int irow = i0 + w * 16 + m;
    float e1p_v = E1p[(size_t)b * TN + irow];
    float e1n_v = E1n[(size_t)b * TN + irow];
    const float* e2pb = E2p + (size_t)b * TN;
    const float* e2nb = E2n + (size_t)b * TN;
    const unsigned short* wtb = Wt + (size_t)b * DD * TN;
    const unsigned int* mrow = rowmask32 + (size_t)irow * 128;

    // staging: 1024 chunks of 8 ushorts; this thread owns chunks tid, tid+512
    int r0 = tid >> 4,          c0 = tid & 15;
    int r1 = (tid + 512) >> 4,  c1 = tid & 15;
    const int jbase = js * 1024;

    f32x4 acc[4];
    #pragma unroll
    for (int dt = 0; dt < 4; ++dt) acc[dt] = (f32x4){0.f, 0.f, 0.f, 0.f};

    // prefetch tile jt=0
    short8 g0 = *reinterpret_cast<const short8*>(wtb + (size_t)r0 * TN + jbase + c0 * 8);
    short8 g1 = *reinterpret_cast<const short8*>(wtb + (size_t)r1 * TN + jbase + c1 * 8);

    for (int jt = 0; jt < 8; ++jt) {
        int j0 = jbase + jt * 128;
        __syncthreads();                                  // prior reads done
        *reinterpret_cast<short8*>(&wt_s[r0 * 136 + c0 * 8]) = g0;
        *reinterpret_cast<short8*>(&wt_s[r1 * 136 + c1 * 8]) = g1;
        if (jt < 7) {                                     // prefetch next tile
            g0 = *reinterpret_cast<const short8*>(wtb + (size_t)r0 * TN + j0 + 128 + c0 * 8);
            g1 = *reinterpret_cast<const short8*>(wtb + (size_t)r1 * TN + j0 + 128 + c1 * 8);
        }
        u32x4 m4 = *reinterpret_cast<const u32x4*>(mrow + (j0 >> 5));
        __syncthreads();                                  // tile visible

        #pragma unroll
        for (int t = 0; t < 4; ++t) {
            int jb = j0 + t * 32 + q * 8;
            unsigned int bytev = (m4[t] >> (q * 8)) & 0xFFu;
            f32x4 p20 = *reinterpret_cast<const f32x4*>(e2pb + jb);
            f32x4 p21 = *reinterpret_cast<const f32x4*>(e2pb + jb + 4);
            f32x4 n20 = *reinterpret_cast<const f32x4*>(e2nb + jb);
            f32x4 n21 = *reinterpret_cast<const f32x4*>(e2nb + jb + 4);
            union { unsigned int u[4]; short8 s; } af;
            #pragma unroll
            for (int jp = 0; jp < 4; ++jp) {
                int j0i = 2 * jp, j1i = 2 * jp + 1;
                float pa  = (j0i < 4) ? p20[j0i] : p21[j0i - 4];
                float na  = (j0i < 4) ? n20[j0i] : n21[j0i - 4];
                float pb2 = (j1i < 4) ? p20[j1i] : p21[j1i - 4];
                float nb2 = (j1i < 4) ? n20[j1i] : n21[j1i - 4];
                float v0 = fmaxf(e1p_v * pa,  e1n_v * na);
                float v1 = fmaxf(e1p_v * pb2, e1n_v * nb2);
                v0 = (bytev & (1u << j0i)) ? v0 : 0.f;
                v1 = (bytev & (1u << j1i)) ? v1 : 0.f;
                __hip_bfloat162 hb = __float22bfloat162_rn(make_float2(v0, v1));
                af.u[jp] = *reinterpret_cast<unsigned int*>(&hb);
            }
            #pragma unroll
            for (int dt = 0; dt < 4; ++dt) {
                short8 bf = *reinterpret_cast<const short8*>(
                    &wt_s[(dt * 16 + m) * 136 + t * 32 + q * 8]);
                acc[dt] = __builtin_amdgcn_mfma_f32_16x16x32_bf16(af.s, bf, acc[dt], 0, 0, 0);
            }
        }
    }

    // C row = q*4+r, col = dt*16+m
    int gbase = i0 + w * 16 + q * 4;
    #pragma unroll
    for (int dt = 0; dt < 4; ++dt) {
        int d = dt * 16 + m;
        #pragma unroll
        for (int r = 0; r < 4; ++r) {
            int g = gbase + r;
            atomicAdd(&hp[((size_t)b * TN + g) * DD + d], acc[dt][r]);
        }
    }
}

// K5: out[b][n][0:64]=elu(hp[b][n]), out[b][n][64:128]=elu(hp[b][n+2048]); float4
__global__ void k5_epi(const float* __restrict__ hp, float* __restrict__ out) {
    int t = blockIdx.x * 256 + threadIdx.x;       // < 524288
    int d4 = t & 31;
    int n = (t >> 5) & 2047;
    int b = t >> 16;
    int g, sd;
    if (d4 < 16) { g = n;        sd = d4 * 4; }
    else         { g = n + NN;   sd = (d4 - 16) * 4; }
    f32x4 v = *reinterpret_cast<const f32x4*>(hp + ((size_t)b * TN + g) * DD + sd);
    f32x4 r;
    #pragma unroll
    for (int c = 0; c < 4; ++c) r[c] = (v[c] > 0.f) ? v[c] : expm1f(v[c]);
    *reinterpret_cast<f32x4*>(out + ((size_t)b * NN + n) * 128 + d4 * 4) = r;
}

extern "C" void kernel_launch(void* const* d_in, const int* in_sizes, int n_in,
                              void* d_out, int out_size, void* d_ws, size_t ws_size,
                              hipStream_t stream) {
    const float* h   = (const float*)d_in[0];
    const float* ht  = (const float*)d_in[1];
    const float* W   = (const float*)d_in[2];
    const float* a1  = (const float*)d_in[3];
    const float* a2  = (const float*)d_in[4];
    const float* adj = (const float*)d_in[5];
    float* out = (float*)d_out;

    char* ws = (char*)d_ws;
    float* Wh          = (float*)(ws);                                   // 8 MB (reused as hp)
    unsigned short* Wt = (unsigned short*)(ws + (8 << 20));              // 4 MB
    float* S           = (float*)(ws + (12 << 20));                      // 128 KB
    float* E1p         = (float*)(ws + (12 << 20) + (128 << 10));
    float* E1n         = (float*)(ws + (12 << 20) + (256 << 10));
    float* E2p         = (float*)(ws + (12 << 20) + (384 << 10));
    float* E2n         = (float*)(ws + (12 << 20) + (512 << 10));
    unsigned long long* rowmask = (unsigned long long*)(ws + (12 << 20) + (640 << 10)); // 2 MB
    const unsigned int* rowmask32 = (const unsigned int*)rowmask;
    float* hp          = Wh;   // Wh dead after k3; reuse as accumulator

    hipMemsetAsync(S, 0, (size_t)BB * TN * sizeof(float), stream);
    k0_mask<<<dim3(4, 128), dim3(256), 0, stream>>>(adj, rowmask);
    k1_wh<<<dim3(BB * TN / 4), dim3(256), 0, stream>>>(h, ht, W, a1, a2, Wh,
                                                       E1p, E1n, E2p, E2n);
    k2_stats<<<dim3(16, 32), dim3(256), 0, stream>>>(rowmask32, E1p, E1n, E2p, E2n, S);
    k3_whn<<<dim3(64, 8), dim3(256), 0, stream>>>(Wh, S, Wt);
    hipMemsetAsync(hp, 0, (size_t)BB * TN * DD * sizeof(float), stream);
    k4_pv<<<dim3(1024), dim3(512), 0, stream>>>(rowmask32, E1p, E1n, E2p, E2n, Wt, hp);
    k5_epi<<<dim3(2048), dim3(256), 0, stream>>>(hp, out);
}